// Round 1
// baseline (367.120 us; speedup 1.0000x reference)
//
#include <hip/hip_runtime.h>

#define TS 2048   // seq len
#define DM 1024   // d_model
#define KD 64     // k
#define NB 4      // batch

// ---------- workspace layout (floats) ----------
// Wcomb [1024][192]  : cols 0-63 Wq=W_pre@Qf, 64-127 Wk=W_pre@Kf, 128-191 Wv
// bcomb [192]        : bq | bk | bv
// QKV   [8192][192]  : per-token Q | Kf-proj | V
// Yb    [8192][64]   : Y (intra then +inter)
// O     [4][64][64][64] : per-chunk outer sums sum_s dec*V(k)Kf(n)
// State [4][64][64][64] : exclusive prefix of O over chunks
#define WCOMB_OFF 0
#define BCOMB_OFF 196608
#define QKV_OFF   196864
#define YB_OFF    1769728
#define O_OFF     2294016
#define ST_OFF    3342592

// ---------------- A: fold filters into weights ----------------
__global__ __launch_bounds__(256) void k_prep_w(
    const float* __restrict__ W_pre, const float* __restrict__ Qf,
    const float* __restrict__ Kf, const float* __restrict__ Wv,
    float* __restrict__ Wcomb) {
  const int d0 = blockIdx.x * 4;
  const int lane = threadIdx.x & 63;
  const int grp = threadIdx.x >> 6;
  float aq[4] = {0.f, 0.f, 0.f, 0.f};
  float ak[4] = {0.f, 0.f, 0.f, 0.f};
  const int t0 = grp * (TS / 4);
  for (int t = t0; t < t0 + TS / 4; ++t) {
    const float qf = Qf[t * KD + lane];
    const float kf = Kf[t * KD + lane];
#pragma unroll
    for (int i = 0; i < 4; ++i) {
      const float w = W_pre[(size_t)(d0 + i) * TS + t];
      aq[i] += w * qf;
      ak[i] += w * kf;
    }
  }
  __shared__ float red[2][4][4][64];  // [qk][d][grp][lane]
#pragma unroll
  for (int i = 0; i < 4; ++i) {
    red[0][i][grp][lane] = aq[i];
    red[1][i][grp][lane] = ak[i];
  }
  __syncthreads();
  const int di = grp;
  const float sq = red[0][di][0][lane] + red[0][di][1][lane] +
                   red[0][di][2][lane] + red[0][di][3][lane];
  const float sk = red[1][di][0][lane] + red[1][di][1][lane] +
                   red[1][di][2][lane] + red[1][di][3][lane];
  Wcomb[(size_t)(d0 + di) * 192 + lane] = sq;
  Wcomb[(size_t)(d0 + di) * 192 + 64 + lane] = sk;
  Wcomb[(size_t)(d0 + di) * 192 + 128 + lane] = Wv[(size_t)(d0 + di) * KD + lane];
}

// ---------------- A2: fold filters into biases ----------------
__global__ __launch_bounds__(256) void k_prep_b(
    const float* __restrict__ b_pre, const float* __restrict__ Qf,
    const float* __restrict__ Kf, const float* __restrict__ bv,
    float* __restrict__ bcomb) {
  const int lane = threadIdx.x & 63;
  const int grp = threadIdx.x >> 6;
  float aq = 0.f, ak = 0.f;
  for (int t = grp * (TS / 4); t < (grp + 1) * (TS / 4); ++t) {
    const float bp = b_pre[t];
    aq += bp * Qf[t * KD + lane];
    ak += bp * Kf[t * KD + lane];
  }
  __shared__ float red[2][4][64];
  red[0][grp][lane] = aq;
  red[1][grp][lane] = ak;
  __syncthreads();
  if (threadIdx.x < 64) {
    bcomb[lane] = red[0][0][lane] + red[0][1][lane] + red[0][2][lane] + red[0][3][lane];
    bcomb[64 + lane] = red[1][0][lane] + red[1][1][lane] + red[1][2][lane] + red[1][3][lane];
    bcomb[128 + lane] = bv[lane];
  }
}

// ---------------- B: QKV = x @ Wcomb + bcomb  (8192x1024 @ 1024x192) ----------------
// block = 192 threads, 32 rows/block, grid 256
__global__ __launch_bounds__(192) void k_qkv(
    const float* __restrict__ x, const float* __restrict__ Wcomb,
    const float* __restrict__ bcomb, float* __restrict__ QKV) {
  const int row0 = blockIdx.x * 32;
  const int tid = threadIdx.x;
  const int cx = tid % 48;   // col group: cols cx*4 .. cx*4+3
  const int ry = tid / 48;   // row group: rows ry*8 .. ry*8+7
  __shared__ float xs[32][36];
  __shared__ float Ws[32][196];
  float acc[8][4];
#pragma unroll
  for (int i = 0; i < 8; ++i)
#pragma unroll
    for (int j = 0; j < 4; ++j) acc[i][j] = 0.f;

  for (int kt = 0; kt < DM / 32; ++kt) {
    __syncthreads();
    // stage x tile: 32 rows x 32 k  (256 float4)
    for (int idx = tid; idx < 256; idx += 192) {
      const int r = idx >> 3, q = (idx & 7) * 4;
      *(float4*)&xs[r][q] =
          *(const float4*)&x[(size_t)(row0 + r) * DM + kt * 32 + q];
    }
    // stage W tile: 32 k x 192 c  (1536 float4)
    for (int idx = tid; idx < 1536; idx += 192) {
      const int kk = idx / 48, cq = (idx % 48) * 4;
      *(float4*)&Ws[kk][cq] = *(const float4*)&Wcomb[(size_t)(kt * 32 + kk) * 192 + cq];
    }
    __syncthreads();
#pragma unroll
    for (int kk = 0; kk < 32; kk += 4) {
      float4 w4[4];
#pragma unroll
      for (int u = 0; u < 4; ++u) w4[u] = *(const float4*)&Ws[kk + u][cx * 4];
#pragma unroll
      for (int i = 0; i < 8; ++i) {
        const float4 x4 = *(const float4*)&xs[ry * 8 + i][kk];
        acc[i][0] += x4.x * w4[0].x + x4.y * w4[1].x + x4.z * w4[2].x + x4.w * w4[3].x;
        acc[i][1] += x4.x * w4[0].y + x4.y * w4[1].y + x4.z * w4[2].y + x4.w * w4[3].y;
        acc[i][2] += x4.x * w4[0].z + x4.y * w4[1].z + x4.z * w4[2].z + x4.w * w4[3].z;
        acc[i][3] += x4.x * w4[0].w + x4.y * w4[1].w + x4.z * w4[2].w + x4.w * w4[3].w;
      }
    }
  }
  const float4 b4 = *(const float4*)&bcomb[cx * 4];
#pragma unroll
  for (int i = 0; i < 8; ++i) {
    float4 o;
    o.x = acc[i][0] + b4.x;
    o.y = acc[i][1] + b4.y;
    o.z = acc[i][2] + b4.z;
    o.w = acc[i][3] + b4.w;
    *(float4*)&QKV[(size_t)(row0 + ry * 8 + i) * 192 + cx * 4] = o;
  }
}

// ---------------- C1: per-chunk intra attention + chunk outer sums ----------------
// grid (64 chunks, 4 batches), 256 threads
__global__ __launch_bounds__(256) void k_chunk(
    const float* __restrict__ QKV, const float* __restrict__ decay,
    float* __restrict__ Yb, float* __restrict__ O) {
  const int c = blockIdx.x;
  const int b = blockIdx.y;
  const int s0 = c * 32;
  const int tid = threadIdx.x;
  __shared__ float Qs[32][68], Ks[32][68], Vs[32][68];
  __shared__ float Ss[32][36];
  __shared__ float dec[32];

  for (int idx = tid; idx < 32 * 16; idx += 256) {
    const int r = idx >> 4, q = (idx & 15) * 4;
    const size_t base = (size_t)(b * TS + s0 + r) * 192;
    *(float4*)&Qs[r][q] = *(const float4*)&QKV[base + q];
    *(float4*)&Ks[r][q] = *(const float4*)&QKV[base + 64 + q];
    *(float4*)&Vs[r][q] = *(const float4*)&QKV[base + 128 + q];
  }
  if (tid < 32) dec[tid] = decay[s0 + tid];
  __syncthreads();

  // S-step: Ss[t][s] = (s<=t) ? dec[s] * (Q[t].V[s]) : 0   (2t x 2s per thread)
  {
    const int sc = (tid & 15) * 2;
    const int tr = (tid >> 4) * 2;
    float a00 = 0.f, a01 = 0.f, a10 = 0.f, a11 = 0.f;
#pragma unroll
    for (int k = 0; k < 64; k += 4) {
      const float4 q0 = *(const float4*)&Qs[tr][k];
      const float4 q1 = *(const float4*)&Qs[tr + 1][k];
      const float4 v0 = *(const float4*)&Vs[sc][k];
      const float4 v1 = *(const float4*)&Vs[sc + 1][k];
      a00 += q0.x * v0.x + q0.y * v0.y + q0.z * v0.z + q0.w * v0.w;
      a01 += q0.x * v1.x + q0.y * v1.y + q0.z * v1.z + q0.w * v1.w;
      a10 += q1.x * v0.x + q1.y * v0.y + q1.z * v0.z + q1.w * v0.w;
      a11 += q1.x * v1.x + q1.y * v1.y + q1.z * v1.z + q1.w * v1.w;
    }
    const float d0 = dec[sc], d1 = dec[sc + 1];
    Ss[tr][sc]         = (sc     <= tr)     ? a00 * d0 : 0.f;
    Ss[tr][sc + 1]     = (sc + 1 <= tr)     ? a01 * d1 : 0.f;
    Ss[tr + 1][sc]     = (sc     <= tr + 1) ? a10 * d0 : 0.f;
    Ss[tr + 1][sc + 1] = (sc + 1 <= tr + 1) ? a11 * d1 : 0.f;
  }

  // O-step: O[k][n] = sum_s dec[s]*V[s][k]*Kf[s][n]   (4k x 4n per thread)
  float o[4][4];
#pragma unroll
  for (int i = 0; i < 4; ++i)
#pragma unroll
    for (int j = 0; j < 4; ++j) o[i][j] = 0.f;
  {
    const int kx = (tid & 15) * 4;
    const int nx = (tid >> 4) * 4;
#pragma unroll
    for (int s = 0; s < 32; ++s) {
      const float ds = dec[s];
      float4 v4 = *(const float4*)&Vs[s][kx];
      const float4 k4 = *(const float4*)&Ks[s][nx];
      v4.x *= ds; v4.y *= ds; v4.z *= ds; v4.w *= ds;
      o[0][0] += v4.x * k4.x; o[0][1] += v4.x * k4.y; o[0][2] += v4.x * k4.z; o[0][3] += v4.x * k4.w;
      o[1][0] += v4.y * k4.x; o[1][1] += v4.y * k4.y; o[1][2] += v4.y * k4.z; o[1][3] += v4.y * k4.w;
      o[2][0] += v4.z * k4.x; o[2][1] += v4.z * k4.y; o[2][2] += v4.z * k4.z; o[2][3] += v4.z * k4.w;
      o[3][0] += v4.w * k4.x; o[3][1] += v4.w * k4.y; o[3][2] += v4.w * k4.z; o[3][3] += v4.w * k4.w;
    }
  }
  __syncthreads();

  // Y-step: Y[t][n] = sum_s Ss[t][s] * Kf[s][n]   (2t x 4n per thread)
  {
    const int nx = (tid & 15) * 4;
    const int tr = (tid >> 4) * 2;
    float y0[4] = {0.f, 0.f, 0.f, 0.f};
    float y1[4] = {0.f, 0.f, 0.f, 0.f};
#pragma unroll
    for (int s = 0; s < 32; s += 4) {
      const float4 sa = *(const float4*)&Ss[tr][s];
      const float4 sb = *(const float4*)&Ss[tr + 1][s];
#pragma unroll
      for (int u = 0; u < 4; ++u) {
        const float4 k4 = *(const float4*)&Ks[s + u][nx];
        const float su0 = (u == 0) ? sa.x : (u == 1) ? sa.y : (u == 2) ? sa.z : sa.w;
        const float su1 = (u == 0) ? sb.x : (u == 1) ? sb.y : (u == 2) ? sb.z : sb.w;
        y0[0] += su0 * k4.x; y0[1] += su0 * k4.y; y0[2] += su0 * k4.z; y0[3] += su0 * k4.w;
        y1[0] += su1 * k4.x; y1[1] += su1 * k4.y; y1[2] += su1 * k4.z; y1[3] += su1 * k4.w;
      }
    }
    float4 w0, w1;
    w0.x = y0[0]; w0.y = y0[1]; w0.z = y0[2]; w0.w = y0[3];
    w1.x = y1[0]; w1.y = y1[1]; w1.z = y1[2]; w1.w = y1[3];
    *(float4*)&Yb[(size_t)(b * TS + s0 + tr) * KD + nx] = w0;
    *(float4*)&Yb[(size_t)(b * TS + s0 + tr + 1) * KD + nx] = w1;
  }

  // write O
  {
    const int kx = (tid & 15) * 4;
    const int nx = (tid >> 4) * 4;
    const size_t base = ((size_t)(b * 64 + c) * 64) * 64;
#pragma unroll
    for (int i = 0; i < 4; ++i) {
      float4 w;
      w.x = o[i][0]; w.y = o[i][1]; w.z = o[i][2]; w.w = o[i][3];
      *(float4*)&O[base + (size_t)(kx + i) * 64 + nx] = w;
    }
  }
}

// ---------------- C2: exclusive prefix over chunks ----------------
// grid (16, 4), 256 threads
__global__ __launch_bounds__(256) void k_scan(const float* __restrict__ O,
                                              float* __restrict__ State) {
  const int e = blockIdx.x * 256 + threadIdx.x;  // 0..4095
  const int b = blockIdx.y;
  const float* op = O + (size_t)b * 64 * 4096 + e;
  float* sp = State + (size_t)b * 64 * 4096 + e;
  float run = 0.f;
  for (int c = 0; c < 64; ++c) {
    sp[(size_t)c * 4096] = run;
    run += op[(size_t)c * 4096];
  }
}

// ---------------- C3: inter-chunk Y += Q @ State ----------------
// grid (64, 4), 256 threads
__global__ __launch_bounds__(256) void k_inter(const float* __restrict__ QKV,
                                               const float* __restrict__ State,
                                               float* __restrict__ Yb) {
  const int tt = blockIdx.x;
  const int b = blockIdx.y;
  const int t0 = tt * 32;
  const int tid = threadIdx.x;
  __shared__ float Sts[64][68];
  __shared__ float Qs[32][68];
  for (int idx = tid; idx < 1024; idx += 256) {  // 4096 floats as float4
    const int k = idx >> 4, n = (idx & 15) * 4;
    *(float4*)&Sts[k][n] =
        *(const float4*)&State[(size_t)(b * 64 + tt) * 4096 + (size_t)k * 64 + n];
  }
  for (int idx = tid; idx < 512; idx += 256) {
    const int r = idx >> 4, q = (idx & 15) * 4;
    *(float4*)&Qs[r][q] = *(const float4*)&QKV[(size_t)(b * TS + t0 + r) * 192 + q];
  }
  __syncthreads();
  const int nx = (tid & 15) * 4;
  const int tr = (tid >> 4) * 2;
  float y0[4] = {0.f, 0.f, 0.f, 0.f};
  float y1[4] = {0.f, 0.f, 0.f, 0.f};
#pragma unroll
  for (int k = 0; k < 64; k += 4) {
    const float4 q0 = *(const float4*)&Qs[tr][k];
    const float4 q1 = *(const float4*)&Qs[tr + 1][k];
#pragma unroll
    for (int u = 0; u < 4; ++u) {
      const float4 st = *(const float4*)&Sts[k + u][nx];
      const float a0 = (u == 0) ? q0.x : (u == 1) ? q0.y : (u == 2) ? q0.z : q0.w;
      const float a1 = (u == 0) ? q1.x : (u == 1) ? q1.y : (u == 2) ? q1.z : q1.w;
      y0[0] += a0 * st.x; y0[1] += a0 * st.y; y0[2] += a0 * st.z; y0[3] += a0 * st.w;
      y1[0] += a1 * st.x; y1[1] += a1 * st.y; y1[2] += a1 * st.z; y1[3] += a1 * st.w;
    }
  }
  float4 p0 = *(const float4*)&Yb[(size_t)(b * TS + t0 + tr) * KD + nx];
  float4 p1 = *(const float4*)&Yb[(size_t)(b * TS + t0 + tr + 1) * KD + nx];
  p0.x += y0[0]; p0.y += y0[1]; p0.z += y0[2]; p0.w += y0[3];
  p1.x += y1[0]; p1.y += y1[1]; p1.z += y1[2]; p1.w += y1[3];
  *(float4*)&Yb[(size_t)(b * TS + t0 + tr) * KD + nx] = p0;
  *(float4*)&Yb[(size_t)(b * TS + t0 + tr + 1) * KD + nx] = p1;
}

// ---------------- D: out = Yb @ W_o + b_o   (8192x64 @ 64x1024) ----------------
// grid 512, 256 threads, 16 rows/block
__global__ __launch_bounds__(256) void k_out(const float* __restrict__ Yb,
                                             const float* __restrict__ Wo,
                                             const float* __restrict__ bo,
                                             float* __restrict__ out) {
  const int row0 = blockIdx.x * 16;
  const int tid = threadIdx.x;
  __shared__ float Ys[16][68];
  {
    const int r = tid >> 4, q = (tid & 15) * 4;
    *(float4*)&Ys[r][q] = *(const float4*)&Yb[(size_t)(row0 + r) * KD + q];
  }
  __syncthreads();
  const int d0 = tid * 4;
  float acc[16][4];
#pragma unroll
  for (int r = 0; r < 16; ++r)
#pragma unroll
    for (int j = 0; j < 4; ++j) acc[r][j] = 0.f;
  for (int k = 0; k < 64; k += 4) {
    const float4 w0 = *(const float4*)&Wo[(size_t)(k + 0) * DM + d0];
    const float4 w1 = *(const float4*)&Wo[(size_t)(k + 1) * DM + d0];
    const float4 w2 = *(const float4*)&Wo[(size_t)(k + 2) * DM + d0];
    const float4 w3 = *(const float4*)&Wo[(size_t)(k + 3) * DM + d0];
#pragma unroll
    for (int r = 0; r < 16; ++r) {
      const float4 ys = *(const float4*)&Ys[r][k];
      acc[r][0] += ys.x * w0.x + ys.y * w1.x + ys.z * w2.x + ys.w * w3.x;
      acc[r][1] += ys.x * w0.y + ys.y * w1.y + ys.z * w2.y + ys.w * w3.y;
      acc[r][2] += ys.x * w0.z + ys.y * w1.z + ys.z * w2.z + ys.w * w3.z;
      acc[r][3] += ys.x * w0.w + ys.y * w1.w + ys.z * w2.w + ys.w * w3.w;
    }
  }
  const float4 b4 = *(const float4*)&bo[d0];
#pragma unroll
  for (int r = 0; r < 16; ++r) {
    float4 w;
    w.x = acc[r][0] + b4.x;
    w.y = acc[r][1] + b4.y;
    w.z = acc[r][2] + b4.z;
    w.w = acc[r][3] + b4.w;
    *(float4*)&out[(size_t)(row0 + r) * DM + d0] = w;
  }
}

extern "C" void kernel_launch(void* const* d_in, const int* in_sizes, int n_in,
                              void* d_out, int out_size, void* d_ws, size_t ws_size,
                              hipStream_t stream) {
  const float* x     = (const float*)d_in[0];  // [4,2048,1024]
  const float* W_pre = (const float*)d_in[1];  // [1024,2048]
  const float* b_pre = (const float*)d_in[2];  // [2048]
  const float* Qf    = (const float*)d_in[3];  // [2048,64]
  const float* Kf    = (const float*)d_in[4];  // [2048,64]
  const float* W_v   = (const float*)d_in[5];  // [1024,64]
  const float* b_v   = (const float*)d_in[6];  // [64]
  const float* W_o   = (const float*)d_in[7];  // [64,1024]
  const float* b_o   = (const float*)d_in[8];  // [1024]
  const float* decay = (const float*)d_in[9];  // [2048]
  float* out = (float*)d_out;
  float* ws = (float*)d_ws;

  float* Wcomb = ws + WCOMB_OFF;
  float* bcomb = ws + BCOMB_OFF;
  float* QKV   = ws + QKV_OFF;
  float* Yb    = ws + YB_OFF;
  float* O     = ws + O_OFF;
  float* St    = ws + ST_OFF;

  k_prep_w<<<dim3(DM / 4), 256, 0, stream>>>(W_pre, Qf, Kf, W_v, Wcomb);
  k_prep_b<<<dim3(1), 256, 0, stream>>>(b_pre, Qf, Kf, b_v, bcomb);
  k_qkv<<<dim3(NB * TS / 32), 192, 0, stream>>>(x, Wcomb, bcomb, QKV);
  k_chunk<<<dim3(TS / 32, NB), 256, 0, stream>>>(QKV, decay, Yb, O);
  k_scan<<<dim3(16, NB), 256, 0, stream>>>(O, St);
  k_inter<<<dim3(TS / 32, NB), 256, 0, stream>>>(QKV, St, Yb);
  k_out<<<dim3(NB * TS / 16), 256, 0, stream>>>(Yb, W_o, b_o, out);
}

// Round 2
// 244.178 us; speedup vs baseline: 1.5035x; 1.5035x over previous
//
#include <hip/hip_runtime.h>

#define TS 2048   // seq len
#define DM 1024   // d_model
#define KD 64     // k
#define NB 4      // batch

// ---------- workspace layout (float offsets) ----------
// WT_hi [192][1024] ushort : rows 0-63 Wq^T, 64-127 Wk^T, 128-191 Wv^T (bf16 hi)
// WT_lo [192][1024] ushort : bf16 residual (lo)
// bcomb [192] f32          : bq | bk | bv
// QKV   [8192][192] f32    : per-token Q | K | V
// P     [4][8192][192] f32 : split-K partials (dead after k_red; O/St/Yb overlay it)
#define WTH_OFF 0
#define WTL_OFF 98304
#define BC_OFF  196608
#define QKV_OFF 196864
#define P_OFF   1769728
#define O_OFF   (P_OFF)
#define ST_OFF  (P_OFF + 1048576)
#define YB_OFF  (P_OFF + 2097152)

typedef __attribute__((ext_vector_type(8))) short bf16x8;
typedef __attribute__((ext_vector_type(4))) float f32x4;

__device__ __forceinline__ ushort f2bf(float f) {
  unsigned u = __float_as_uint(f);
  unsigned r = u + 0x7FFFu + ((u >> 16) & 1u);
  return (ushort)(r >> 16);
}
__device__ __forceinline__ float bf2f(ushort h) {
  return __uint_as_float(((unsigned)h) << 16);
}

// ---------------- A: fold filters into weights, emit transposed bf16 hi/lo ----------------
__global__ __launch_bounds__(256) void k_prep_w(
    const float* __restrict__ W_pre, const float* __restrict__ Qf,
    const float* __restrict__ Kf, const float* __restrict__ Wv,
    ushort* __restrict__ WT_hi, ushort* __restrict__ WT_lo) {
  const int d0 = blockIdx.x * 4;
  const int lane = threadIdx.x & 63;
  const int grp = threadIdx.x >> 6;
  float aq[4] = {0.f, 0.f, 0.f, 0.f};
  float ak[4] = {0.f, 0.f, 0.f, 0.f};
  const int t0 = grp * (TS / 4);
  for (int t = t0; t < t0 + TS / 4; ++t) {
    const float qf = Qf[t * KD + lane];
    const float kf = Kf[t * KD + lane];
#pragma unroll
    for (int i = 0; i < 4; ++i) {
      const float w = W_pre[(size_t)(d0 + i) * TS + t];
      aq[i] += w * qf;
      ak[i] += w * kf;
    }
  }
  __shared__ float red[2][4][4][64];  // [qk][d][grp][lane]
#pragma unroll
  for (int i = 0; i < 4; ++i) {
    red[0][i][grp][lane] = aq[i];
    red[1][i][grp][lane] = ak[i];
  }
  __syncthreads();
  const int di = grp;
  const int d = d0 + di;
  const float sq = red[0][di][0][lane] + red[0][di][1][lane] +
                   red[0][di][2][lane] + red[0][di][3][lane];
  const float sk = red[1][di][0][lane] + red[1][di][1][lane] +
                   red[1][di][2][lane] + red[1][di][3][lane];
  const float wv = Wv[(size_t)d * KD + lane];
  const ushort qh = f2bf(sq), kh = f2bf(sk), vh = f2bf(wv);
  WT_hi[(size_t)(lane) * DM + d] = qh;
  WT_hi[(size_t)(64 + lane) * DM + d] = kh;
  WT_hi[(size_t)(128 + lane) * DM + d] = vh;
  WT_lo[(size_t)(lane) * DM + d] = f2bf(sq - bf2f(qh));
  WT_lo[(size_t)(64 + lane) * DM + d] = f2bf(sk - bf2f(kh));
  WT_lo[(size_t)(128 + lane) * DM + d] = f2bf(wv - bf2f(vh));
}

// ---------------- A2: fold filters into biases ----------------
__global__ __launch_bounds__(256) void k_prep_b(
    const float* __restrict__ b_pre, const float* __restrict__ Qf,
    const float* __restrict__ Kf, const float* __restrict__ bv,
    float* __restrict__ bcomb) {
  const int lane = threadIdx.x & 63;
  const int grp = threadIdx.x >> 6;
  float aq = 0.f, ak = 0.f;
  for (int t = grp * (TS / 4); t < (grp + 1) * (TS / 4); ++t) {
    const float bp = b_pre[t];
    aq += bp * Qf[t * KD + lane];
    ak += bp * Kf[t * KD + lane];
  }
  __shared__ float red[2][4][64];
  red[0][grp][lane] = aq;
  red[1][grp][lane] = ak;
  __syncthreads();
  if (threadIdx.x < 64) {
    bcomb[lane] = red[0][0][lane] + red[0][1][lane] + red[0][2][lane] + red[0][3][lane];
    bcomb[64 + lane] = red[1][0][lane] + red[1][1][lane] + red[1][2][lane] + red[1][3][lane];
    bcomb[128 + lane] = bv[lane];
  }
}

// ---------------- B: split-K MFMA bf16x3 GEMM  P[ks] = x[:, ks*256:+256] @ W ----------------
// grid (128 row-tiles, 4 k-slices), 256 threads (4 waves)
// wave w: rows bx*64..+63 (4 m-tiles), cols w*48..+47 (3 n-tiles)
__global__ __launch_bounds__(256) void k_qkv(
    const float* __restrict__ x, const ushort* __restrict__ WT_hi,
    const ushort* __restrict__ WT_lo, float* __restrict__ P) {
  const int row0 = blockIdx.x * 64;
  const int ks = blockIdx.y;
  const int tid = threadIdx.x;
  const int wave = tid >> 6, lane = tid & 63;
  const int quad = lane >> 4, l15 = lane & 15;
  const int n0 = wave * 48;
  // row layout: [32 hi bf16][32 lo bf16][8 pad] = 72 ushort = 144 B (16B-mult, 2-way banks)
  __shared__ ushort As[64 * 72];
  __shared__ ushort Bs[192 * 72];
  f32x4 acc[4][3];
#pragma unroll
  for (int mt = 0; mt < 4; ++mt)
#pragma unroll
    for (int nt = 0; nt < 3; ++nt) acc[mt][nt] = (f32x4){0.f, 0.f, 0.f, 0.f};

  for (int step = 0; step < 8; ++step) {
    const int kk = ks * 256 + step * 32;
    __syncthreads();
    // stage A: 64 rows x 32 k fp32 -> hi/lo bf16 (512 float4, 2/thread)
#pragma unroll
    for (int i = 0; i < 2; ++i) {
      const int idx = i * 256 + tid;
      const int r = idx >> 3, c4 = (idx & 7) * 4;
      const float4 v = *(const float4*)&x[(size_t)(row0 + r) * DM + kk + c4];
      const ushort h0 = f2bf(v.x), h1 = f2bf(v.y), h2 = f2bf(v.z), h3 = f2bf(v.w);
      *(ushort4*)&As[r * 72 + c4] = make_ushort4(h0, h1, h2, h3);
      *(ushort4*)&As[r * 72 + 32 + c4] = make_ushort4(
          f2bf(v.x - bf2f(h0)), f2bf(v.y - bf2f(h1)),
          f2bf(v.z - bf2f(h2)), f2bf(v.w - bf2f(h3)));
    }
    // stage B: 192 n-rows x 32 k, hi+lo (1536 16B chunks, 6/thread)
#pragma unroll
    for (int i = 0; i < 6; ++i) {
      const int idx = i * 256 + tid;
      const int half = idx >= 768;
      const int j = half ? idx - 768 : idx;
      const int n = j >> 2, ch = j & 3;
      const ushort* src = (half ? WT_lo : WT_hi) + (size_t)n * DM + kk + ch * 8;
      *(float4*)&Bs[n * 72 + half * 32 + ch * 8] = *(const float4*)src;
    }
    __syncthreads();
    bf16x8 a_h[4], a_l[4], b_h[3], b_l[3];
#pragma unroll
    for (int mt = 0; mt < 4; ++mt) {
      const ushort* p = &As[(mt * 16 + l15) * 72 + quad * 8];
      a_h[mt] = *(const bf16x8*)p;
      a_l[mt] = *(const bf16x8*)(p + 32);
    }
#pragma unroll
    for (int nt = 0; nt < 3; ++nt) {
      const ushort* p = &Bs[(n0 + nt * 16 + l15) * 72 + quad * 8];
      b_h[nt] = *(const bf16x8*)p;
      b_l[nt] = *(const bf16x8*)(p + 32);
    }
#pragma unroll
    for (int mt = 0; mt < 4; ++mt)
#pragma unroll
      for (int nt = 0; nt < 3; ++nt) {
        acc[mt][nt] = __builtin_amdgcn_mfma_f32_16x16x32_bf16(a_h[mt], b_h[nt], acc[mt][nt], 0, 0, 0);
        acc[mt][nt] = __builtin_amdgcn_mfma_f32_16x16x32_bf16(a_h[mt], b_l[nt], acc[mt][nt], 0, 0, 0);
        acc[mt][nt] = __builtin_amdgcn_mfma_f32_16x16x32_bf16(a_l[mt], b_h[nt], acc[mt][nt], 0, 0, 0);
      }
  }
  float* Pp = P + (size_t)ks * TS * NB * 192;
#pragma unroll
  for (int mt = 0; mt < 4; ++mt) {
    const int rbase = row0 + mt * 16 + quad * 4;
#pragma unroll
    for (int nt = 0; nt < 3; ++nt) {
      const int col = n0 + nt * 16 + l15;
#pragma unroll
      for (int r = 0; r < 4; ++r)
        Pp[(size_t)(rbase + r) * 192 + col] = acc[mt][nt][r];
    }
  }
}

// ---------------- B2: reduce split-K partials + bias ----------------
__global__ __launch_bounds__(256) void k_red(const float* __restrict__ P,
                                             const float* __restrict__ bcomb,
                                             float* __restrict__ QKV) {
  const int f4 = blockIdx.x * 256 + threadIdx.x;  // float4 index, 0..393215
  const int g = f4 * 4;
  const int col = g % 192;
  const size_t NTOT = (size_t)TS * NB * 192;
  float4 a = *(const float4*)&P[g];
  const float4 b = *(const float4*)&P[NTOT + g];
  const float4 c = *(const float4*)&P[2 * NTOT + g];
  const float4 d = *(const float4*)&P[3 * NTOT + g];
  const float4 bi = *(const float4*)&bcomb[col];
  a.x += b.x + c.x + d.x + bi.x;
  a.y += b.y + c.y + d.y + bi.y;
  a.z += b.z + c.z + d.z + bi.z;
  a.w += b.w + c.w + d.w + bi.w;
  *(float4*)&QKV[g] = a;
}

// ---------------- C1: per-chunk intra attention + chunk outer sums ----------------
__global__ __launch_bounds__(256) void k_chunk(
    const float* __restrict__ QKV, const float* __restrict__ decay,
    float* __restrict__ Yb, float* __restrict__ O) {
  const int c = blockIdx.x;
  const int b = blockIdx.y;
  const int s0 = c * 32;
  const int tid = threadIdx.x;
  __shared__ float Qs[32][68], Ks[32][68], Vs[32][68];
  __shared__ float Ss[32][36];
  __shared__ float dec[32];

  for (int idx = tid; idx < 32 * 16; idx += 256) {
    const int r = idx >> 4, q = (idx & 15) * 4;
    const size_t base = (size_t)(b * TS + s0 + r) * 192;
    *(float4*)&Qs[r][q] = *(const float4*)&QKV[base + q];
    *(float4*)&Ks[r][q] = *(const float4*)&QKV[base + 64 + q];
    *(float4*)&Vs[r][q] = *(const float4*)&QKV[base + 128 + q];
  }
  if (tid < 32) dec[tid] = decay[s0 + tid];
  __syncthreads();

  {
    const int sc = (tid & 15) * 2;
    const int tr = (tid >> 4) * 2;
    float a00 = 0.f, a01 = 0.f, a10 = 0.f, a11 = 0.f;
#pragma unroll
    for (int k = 0; k < 64; k += 4) {
      const float4 q0 = *(const float4*)&Qs[tr][k];
      const float4 q1 = *(const float4*)&Qs[tr + 1][k];
      const float4 v0 = *(const float4*)&Vs[sc][k];
      const float4 v1 = *(const float4*)&Vs[sc + 1][k];
      a00 += q0.x * v0.x + q0.y * v0.y + q0.z * v0.z + q0.w * v0.w;
      a01 += q0.x * v1.x + q0.y * v1.y + q0.z * v1.z + q0.w * v1.w;
      a10 += q1.x * v0.x + q1.y * v0.y + q1.z * v0.z + q1.w * v0.w;
      a11 += q1.x * v1.x + q1.y * v1.y + q1.z * v1.z + q1.w * v1.w;
    }
    const float d0 = dec[sc], d1 = dec[sc + 1];
    Ss[tr][sc]         = (sc     <= tr)     ? a00 * d0 : 0.f;
    Ss[tr][sc + 1]     = (sc + 1 <= tr)     ? a01 * d1 : 0.f;
    Ss[tr + 1][sc]     = (sc     <= tr + 1) ? a10 * d0 : 0.f;
    Ss[tr + 1][sc + 1] = (sc + 1 <= tr + 1) ? a11 * d1 : 0.f;
  }

  float o[4][4];
#pragma unroll
  for (int i = 0; i < 4; ++i)
#pragma unroll
    for (int j = 0; j < 4; ++j) o[i][j] = 0.f;
  {
    const int kx = (tid & 15) * 4;
    const int nx = (tid >> 4) * 4;
#pragma unroll
    for (int s = 0; s < 32; ++s) {
      const float ds = dec[s];
      float4 v4 = *(const float4*)&Vs[s][kx];
      const float4 k4 = *(const float4*)&Ks[s][nx];
      v4.x *= ds; v4.y *= ds; v4.z *= ds; v4.w *= ds;
      o[0][0] += v4.x * k4.x; o[0][1] += v4.x * k4.y; o[0][2] += v4.x * k4.z; o[0][3] += v4.x * k4.w;
      o[1][0] += v4.y * k4.x; o[1][1] += v4.y * k4.y; o[1][2] += v4.y * k4.z; o[1][3] += v4.y * k4.w;
      o[2][0] += v4.z * k4.x; o[2][1] += v4.z * k4.y; o[2][2] += v4.z * k4.z; o[2][3] += v4.z * k4.w;
      o[3][0] += v4.w * k4.x; o[3][1] += v4.w * k4.y; o[3][2] += v4.w * k4.z; o[3][3] += v4.w * k4.w;
    }
  }
  __syncthreads();

  {
    const int nx = (tid & 15) * 4;
    const int tr = (tid >> 4) * 2;
    float y0[4] = {0.f, 0.f, 0.f, 0.f};
    float y1[4] = {0.f, 0.f, 0.f, 0.f};
#pragma unroll
    for (int s = 0; s < 32; s += 4) {
      const float4 sa = *(const float4*)&Ss[tr][s];
      const float4 sb = *(const float4*)&Ss[tr + 1][s];
#pragma unroll
      for (int u = 0; u < 4; ++u) {
        const float4 k4 = *(const float4*)&Ks[s + u][nx];
        const float su0 = (u == 0) ? sa.x : (u == 1) ? sa.y : (u == 2) ? sa.z : sa.w;
        const float su1 = (u == 0) ? sb.x : (u == 1) ? sb.y : (u == 2) ? sb.z : sb.w;
        y0[0] += su0 * k4.x; y0[1] += su0 * k4.y; y0[2] += su0 * k4.z; y0[3] += su0 * k4.w;
        y1[0] += su1 * k4.x; y1[1] += su1 * k4.y; y1[2] += su1 * k4.z; y1[3] += su1 * k4.w;
      }
    }
    float4 w0, w1;
    w0.x = y0[0]; w0.y = y0[1]; w0.z = y0[2]; w0.w = y0[3];
    w1.x = y1[0]; w1.y = y1[1]; w1.z = y1[2]; w1.w = y1[3];
    *(float4*)&Yb[(size_t)(b * TS + s0 + tr) * KD + nx] = w0;
    *(float4*)&Yb[(size_t)(b * TS + s0 + tr + 1) * KD + nx] = w1;
  }

  {
    const int kx = (tid & 15) * 4;
    const int nx = (tid >> 4) * 4;
    const size_t base = ((size_t)(b * 64 + c) * 64) * 64;
#pragma unroll
    for (int i = 0; i < 4; ++i) {
      float4 w;
      w.x = o[i][0]; w.y = o[i][1]; w.z = o[i][2]; w.w = o[i][3];
      *(float4*)&O[base + (size_t)(kx + i) * 64 + nx] = w;
    }
  }
}

// ---------------- C2: exclusive prefix over chunks ----------------
__global__ __launch_bounds__(256) void k_scan(const float* __restrict__ O,
                                              float* __restrict__ State) {
  const int e = blockIdx.x * 256 + threadIdx.x;
  const int b = blockIdx.y;
  const float* op = O + (size_t)b * 64 * 4096 + e;
  float* sp = State + (size_t)b * 64 * 4096 + e;
  float run = 0.f;
  for (int c = 0; c < 64; ++c) {
    sp[(size_t)c * 4096] = run;
    run += op[(size_t)c * 4096];
  }
}

// ---------------- C3: inter-chunk Y += Q @ State ----------------
__global__ __launch_bounds__(256) void k_inter(const float* __restrict__ QKV,
                                               const float* __restrict__ State,
                                               float* __restrict__ Yb) {
  const int tt = blockIdx.x;
  const int b = blockIdx.y;
  const int t0 = tt * 32;
  const int tid = threadIdx.x;
  __shared__ float Sts[64][68];
  __shared__ float Qs[32][68];
  for (int idx = tid; idx < 1024; idx += 256) {
    const int k = idx >> 4, n = (idx & 15) * 4;
    *(float4*)&Sts[k][n] =
        *(const float4*)&State[(size_t)(b * 64 + tt) * 4096 + (size_t)k * 64 + n];
  }
  for (int idx = tid; idx < 512; idx += 256) {
    const int r = idx >> 4, q = (idx & 15) * 4;
    *(float4*)&Qs[r][q] = *(const float4*)&QKV[(size_t)(b * TS + t0 + r) * 192 + q];
  }
  __syncthreads();
  const int nx = (tid & 15) * 4;
  const int tr = (tid >> 4) * 2;
  float y0[4] = {0.f, 0.f, 0.f, 0.f};
  float y1[4] = {0.f, 0.f, 0.f, 0.f};
#pragma unroll
  for (int k = 0; k < 64; k += 4) {
    const float4 q0 = *(const float4*)&Qs[tr][k];
    const float4 q1 = *(const float4*)&Qs[tr + 1][k];
#pragma unroll
    for (int u = 0; u < 4; ++u) {
      const float4 st = *(const float4*)&Sts[k + u][nx];
      const float a0 = (u == 0) ? q0.x : (u == 1) ? q0.y : (u == 2) ? q0.z : q0.w;
      const float a1 = (u == 0) ? q1.x : (u == 1) ? q1.y : (u == 2) ? q1.z : q1.w;
      y0[0] += a0 * st.x; y0[1] += a0 * st.y; y0[2] += a0 * st.z; y0[3] += a0 * st.w;
      y1[0] += a1 * st.x; y1[1] += a1 * st.y; y1[2] += a1 * st.z; y1[3] += a1 * st.w;
    }
  }
  float4 p0 = *(const float4*)&Yb[(size_t)(b * TS + t0 + tr) * KD + nx];
  float4 p1 = *(const float4*)&Yb[(size_t)(b * TS + t0 + tr + 1) * KD + nx];
  p0.x += y0[0]; p0.y += y0[1]; p0.z += y0[2]; p0.w += y0[3];
  p1.x += y1[0]; p1.y += y1[1]; p1.z += y1[2]; p1.w += y1[3];
  *(float4*)&Yb[(size_t)(b * TS + t0 + tr) * KD + nx] = p0;
  *(float4*)&Yb[(size_t)(b * TS + t0 + tr + 1) * KD + nx] = p1;
}

// ---------------- D: out = Yb @ W_o + b_o ----------------
__global__ __launch_bounds__(256) void k_out(const float* __restrict__ Yb,
                                             const float* __restrict__ Wo,
                                             const float* __restrict__ bo,
                                             float* __restrict__ out) {
  const int row0 = blockIdx.x * 16;
  const int tid = threadIdx.x;
  __shared__ float Ys[16][68];
  {
    const int r = tid >> 4, q = (tid & 15) * 4;
    *(float4*)&Ys[r][q] = *(const float4*)&Yb[(size_t)(row0 + r) * KD + q];
  }
  __syncthreads();
  const int d0 = tid * 4;
  float acc[16][4];
#pragma unroll
  for (int r = 0; r < 16; ++r)
#pragma unroll
    for (int j = 0; j < 4; ++j) acc[r][j] = 0.f;
  for (int k = 0; k < 64; k += 4) {
    const float4 w0 = *(const float4*)&Wo[(size_t)(k + 0) * DM + d0];
    const float4 w1 = *(const float4*)&Wo[(size_t)(k + 1) * DM + d0];
    const float4 w2 = *(const float4*)&Wo[(size_t)(k + 2) * DM + d0];
    const float4 w3 = *(const float4*)&Wo[(size_t)(k + 3) * DM + d0];
#pragma unroll
    for (int r = 0; r < 16; ++r) {
      const float4 ys = *(const float4*)&Ys[r][k];
      acc[r][0] += ys.x * w0.x + ys.y * w1.x + ys.z * w2.x + ys.w * w3.x;
      acc[r][1] += ys.x * w0.y + ys.y * w1.y + ys.z * w2.y + ys.w * w3.y;
      acc[r][2] += ys.x * w0.z + ys.y * w1.z + ys.z * w2.z + ys.w * w3.z;
      acc[r][3] += ys.x * w0.w + ys.y * w1.w + ys.z * w2.w + ys.w * w3.w;
    }
  }
  const float4 b4 = *(const float4*)&bo[d0];
#pragma unroll
  for (int r = 0; r < 16; ++r) {
    float4 w;
    w.x = acc[r][0] + b4.x;
    w.y = acc[r][1] + b4.y;
    w.z = acc[r][2] + b4.z;
    w.w = acc[r][3] + b4.w;
    *(float4*)&out[(size_t)(row0 + r) * DM + d0] = w;
  }
}

extern "C" void kernel_launch(void* const* d_in, const int* in_sizes, int n_in,
                              void* d_out, int out_size, void* d_ws, size_t ws_size,
                              hipStream_t stream) {
  const float* x     = (const float*)d_in[0];
  const float* W_pre = (const float*)d_in[1];
  const float* b_pre = (const float*)d_in[2];
  const float* Qf    = (const float*)d_in[3];
  const float* Kf    = (const float*)d_in[4];
  const float* W_v   = (const float*)d_in[5];
  const float* b_v   = (const float*)d_in[6];
  const float* W_o   = (const float*)d_in[7];
  const float* b_o   = (const float*)d_in[8];
  const float* decay = (const float*)d_in[9];
  float* out = (float*)d_out;
  float* ws = (float*)d_ws;

  ushort* WT_hi = (ushort*)(ws + WTH_OFF);
  ushort* WT_lo = (ushort*)(ws + WTL_OFF);
  float* bcomb = ws + BC_OFF;
  float* QKV   = ws + QKV_OFF;
  float* P     = ws + P_OFF;
  float* O     = ws + O_OFF;
  float* St    = ws + ST_OFF;
  float* Yb    = ws + YB_OFF;

  k_prep_w<<<dim3(DM / 4), 256, 0, stream>>>(W_pre, Qf, Kf, W_v, WT_hi, WT_lo);
  k_prep_b<<<dim3(1), 256, 0, stream>>>(b_pre, Qf, Kf, b_v, bcomb);
  k_qkv<<<dim3(NB * TS / 64, 4), 256, 0, stream>>>(x, WT_hi, WT_lo, P);
  k_red<<<dim3(NB * TS * 192 / 4 / 256), 256, 0, stream>>>(P, bcomb, QKV);
  k_chunk<<<dim3(TS / 32, NB), 256, 0, stream>>>(QKV, decay, Yb, O);
  k_scan<<<dim3(16, NB), 256, 0, stream>>>(O, St);
  k_inter<<<dim3(TS / 32, NB), 256, 0, stream>>>(QKV, St, Yb);
  k_out<<<dim3(NB * TS / 16), 256, 0, stream>>>(Yb, W_o, b_o, out);
}

// Round 4
// 214.738 us; speedup vs baseline: 1.7096x; 1.1371x over previous
//
#include <hip/hip_runtime.h>

#define TS 2048   // seq len
#define DM 1024   // d_model
#define KD 64     // k
#define NB 4      // batch

// ---------- workspace layout (float offsets) ----------
// WT_hi [192][1024] ushort : rows 0-63 Wq^T, 64-127 Wk^T, 128-191 Wv^T (bf16 hi)
// WT_lo [192][1024] ushort : bf16 residual (lo)
// bcomb [192] f32          : bq | bk | bv
// QKV   [8192][192] f32    : per-token Q | K | V
// P     [4][8192][192] f32 : split-K partials (k_qkv->k_red); O/St/Yb overlay it
//                            after k_red. NOTE (R3 lesson): do NOT stage
//                            short-lived prep intermediates in ws early in the
//                            launch sequence — replay divergence.
#define WTH_OFF 0
#define WTL_OFF 98304
#define BC_OFF  196608
#define QKV_OFF 196864
#define P_OFF   1769728
#define O_OFF   (P_OFF)
#define ST_OFF  (P_OFF + 1048576)
#define YB_OFF  (P_OFF + 2097152)

typedef __attribute__((ext_vector_type(8))) short bf16x8;
typedef __attribute__((ext_vector_type(4))) float f32x4;

__device__ __forceinline__ ushort f2bf(float f) {
  unsigned u = __float_as_uint(f);
  unsigned r = u + 0x7FFFu + ((u >> 16) & 1u);
  return (ushort)(r >> 16);
}
__device__ __forceinline__ float bf2f(ushort h) {
  return __uint_as_float(((unsigned)h) << 16);
}

// ---------------- A: fold filters into weights (+bias in block 0) ----------------
// grid 512, 512 threads: block = 2 d-rows, 8-way t-split (grp), 64 lanes = n
__global__ __launch_bounds__(512) void k_prep_w(
    const float* __restrict__ W_pre, const float* __restrict__ Qf,
    const float* __restrict__ Kf, const float* __restrict__ Wv,
    const float* __restrict__ b_pre, const float* __restrict__ bv,
    ushort* __restrict__ WT_hi, ushort* __restrict__ WT_lo,
    float* __restrict__ bcomb) {
  const int d0 = blockIdx.x * 2;
  const int lane = threadIdx.x & 63;
  const int grp = threadIdx.x >> 6;  // 0..7 -> t slice of 256
  const int t0 = grp * 256;
  float aq[2] = {0.f, 0.f};
  float ak[2] = {0.f, 0.f};
  for (int t = t0; t < t0 + 256; ++t) {
    const float qf = Qf[(size_t)t * KD + lane];
    const float kf = Kf[(size_t)t * KD + lane];
    const float w0 = W_pre[(size_t)d0 * TS + t];        // wave-uniform
    const float w1 = W_pre[(size_t)(d0 + 1) * TS + t];  // wave-uniform
    aq[0] += w0 * qf;
    ak[0] += w0 * kf;
    aq[1] += w1 * qf;
    ak[1] += w1 * kf;
  }
  __shared__ float red[2][2][8][64];  // [qk][d][grp][lane]
#pragma unroll
  for (int i = 0; i < 2; ++i) {
    red[0][i][grp][lane] = aq[i];
    red[1][i][grp][lane] = ak[i];
  }
  __syncthreads();
  if (threadIdx.x < 256) {
    const int l = threadIdx.x & 63;
    const int di = (threadIdx.x >> 6) & 1;
    const int h = threadIdx.x >> 7;  // 0=q, 1=k
    float s = 0.f;
#pragma unroll
    for (int g = 0; g < 8; ++g) s += red[h][di][g][l];
    const ushort hi = f2bf(s);
    WT_hi[(size_t)(h * 64 + l) * DM + d0 + di] = hi;
    WT_lo[(size_t)(h * 64 + l) * DM + d0 + di] = f2bf(s - bf2f(hi));
  } else if (threadIdx.x < 384) {
    const int l = threadIdx.x & 63;
    const int di = (threadIdx.x >> 6) & 1;
    const float v = Wv[(size_t)(d0 + di) * KD + l];
    const ushort hi = f2bf(v);
    WT_hi[(size_t)(128 + l) * DM + d0 + di] = hi;
    WT_lo[(size_t)(128 + l) * DM + d0 + di] = f2bf(v - bf2f(hi));
  }
  // block 0 additionally computes bcomb = [b_pre@Qf | b_pre@Kf | bv]
  if (blockIdx.x == 0) {
    float bq = 0.f, bk = 0.f;
    for (int t = t0; t < t0 + 256; ++t) {
      const float bp = b_pre[t];
      bq += bp * Qf[(size_t)t * KD + lane];
      bk += bp * Kf[(size_t)t * KD + lane];
    }
    __syncthreads();  // reuse red after main reduction reads done
    red[0][0][grp][lane] = bq;
    red[0][1][grp][lane] = bk;
    __syncthreads();
    if (threadIdx.x < 128) {
      const int h = threadIdx.x >> 6;
      const int l = threadIdx.x & 63;
      float s = 0.f;
#pragma unroll
      for (int g = 0; g < 8; ++g) s += red[0][h][g][l];
      bcomb[h * 64 + l] = s;
    } else if (threadIdx.x < 192) {
      const int l = threadIdx.x & 63;
      bcomb[128 + l] = bv[l];
    }
  }
}

// ---------------- B: split-K MFMA bf16x3 GEMM  P[ks] = x[:, ks*256:+256] @ W ----------------
// grid (128 row-tiles, 4 k-slices), 256 threads (4 waves)
__global__ __launch_bounds__(256) void k_qkv(
    const float* __restrict__ x, const ushort* __restrict__ WT_hi,
    const ushort* __restrict__ WT_lo, float* __restrict__ P) {
  const int row0 = blockIdx.x * 64;
  const int ks = blockIdx.y;
  const int tid = threadIdx.x;
  const int wave = tid >> 6, lane = tid & 63;
  const int quad = lane >> 4, l15 = lane & 15;
  const int n0 = wave * 48;
  __shared__ ushort As[64 * 72];
  __shared__ ushort Bs[192 * 72];
  f32x4 acc[4][3];
#pragma unroll
  for (int mt = 0; mt < 4; ++mt)
#pragma unroll
    for (int nt = 0; nt < 3; ++nt) acc[mt][nt] = (f32x4){0.f, 0.f, 0.f, 0.f};

  for (int step = 0; step < 8; ++step) {
    const int kk = ks * 256 + step * 32;
    __syncthreads();
#pragma unroll
    for (int i = 0; i < 2; ++i) {
      const int idx = i * 256 + tid;
      const int r = idx >> 3, c4 = (idx & 7) * 4;
      const float4 v = *(const float4*)&x[(size_t)(row0 + r) * DM + kk + c4];
      const ushort h0 = f2bf(v.x), h1 = f2bf(v.y), h2 = f2bf(v.z), h3 = f2bf(v.w);
      *(ushort4*)&As[r * 72 + c4] = make_ushort4(h0, h1, h2, h3);
      *(ushort4*)&As[r * 72 + 32 + c4] = make_ushort4(
          f2bf(v.x - bf2f(h0)), f2bf(v.y - bf2f(h1)),
          f2bf(v.z - bf2f(h2)), f2bf(v.w - bf2f(h3)));
    }
#pragma unroll
    for (int i = 0; i < 6; ++i) {
      const int idx = i * 256 + tid;
      const int half = idx >= 768;
      const int j = half ? idx - 768 : idx;
      const int n = j >> 2, ch = j & 3;
      const ushort* src = (half ? WT_lo : WT_hi) + (size_t)n * DM + kk + ch * 8;
      *(float4*)&Bs[n * 72 + half * 32 + ch * 8] = *(const float4*)src;
    }
    __syncthreads();
    bf16x8 a_h[4], a_l[4], b_h[3], b_l[3];
#pragma unroll
    for (int mt = 0; mt < 4; ++mt) {
      const ushort* p = &As[(mt * 16 + l15) * 72 + quad * 8];
      a_h[mt] = *(const bf16x8*)p;
      a_l[mt] = *(const bf16x8*)(p + 32);
    }
#pragma unroll
    for (int nt = 0; nt < 3; ++nt) {
      const ushort* p = &Bs[(n0 + nt * 16 + l15) * 72 + quad * 8];
      b_h[nt] = *(const bf16x8*)p;
      b_l[nt] = *(const bf16x8*)(p + 32);
    }
#pragma unroll
    for (int mt = 0; mt < 4; ++mt)
#pragma unroll
      for (int nt = 0; nt < 3; ++nt) {
        acc[mt][nt] = __builtin_amdgcn_mfma_f32_16x16x32_bf16(a_h[mt], b_h[nt], acc[mt][nt], 0, 0, 0);
        acc[mt][nt] = __builtin_amdgcn_mfma_f32_16x16x32_bf16(a_h[mt], b_l[nt], acc[mt][nt], 0, 0, 0);
        acc[mt][nt] = __builtin_amdgcn_mfma_f32_16x16x32_bf16(a_l[mt], b_h[nt], acc[mt][nt], 0, 0, 0);
      }
  }
  float* Pp = P + (size_t)ks * TS * NB * 192;
#pragma unroll
  for (int mt = 0; mt < 4; ++mt) {
    const int rbase = row0 + mt * 16 + quad * 4;
#pragma unroll
    for (int nt = 0; nt < 3; ++nt) {
      const int col = n0 + nt * 16 + l15;
#pragma unroll
      for (int r = 0; r < 4; ++r)
        Pp[(size_t)(rbase + r) * 192 + col] = acc[mt][nt][r];
    }
  }
}

// ---------------- B2: reduce split-K partials + bias ----------------
__global__ __launch_bounds__(256) void k_red(const float* __restrict__ P,
                                             const float* __restrict__ bcomb,
                                             float* __restrict__ QKV) {
  const int f4 = blockIdx.x * 256 + threadIdx.x;
  const int g = f4 * 4;
  const int col = g % 192;
  const size_t NTOT = (size_t)TS * NB * 192;
  float4 a = *(const float4*)&P[g];
  const float4 b = *(const float4*)&P[NTOT + g];
  const float4 c = *(const float4*)&P[2 * NTOT + g];
  const float4 d = *(const float4*)&P[3 * NTOT + g];
  const float4 bi = *(const float4*)&bcomb[col];
  a.x += b.x + c.x + d.x + bi.x;
  a.y += b.y + c.y + d.y + bi.y;
  a.z += b.z + c.z + d.z + bi.z;
  a.w += b.w + c.w + d.w + bi.w;
  *(float4*)&QKV[g] = a;
}

// ---------------- C1: per-chunk intra attention + chunk outer sums ----------------
__global__ __launch_bounds__(256) void k_chunk(
    const float* __restrict__ QKV, const float* __restrict__ decay,
    float* __restrict__ Yb, float* __restrict__ O) {
  const int c = blockIdx.x;
  const int b = blockIdx.y;
  const int s0 = c * 32;
  const int tid = threadIdx.x;
  __shared__ float Qs[32][68], Ks[32][68], Vs[32][68];
  __shared__ float Ss[32][36];
  __shared__ float dec[32];

  for (int idx = tid; idx < 32 * 16; idx += 256) {
    const int r = idx >> 4, q = (idx & 15) * 4;
    const size_t base = (size_t)(b * TS + s0 + r) * 192;
    *(float4*)&Qs[r][q] = *(const float4*)&QKV[base + q];
    *(float4*)&Ks[r][q] = *(const float4*)&QKV[base + 64 + q];
    *(float4*)&Vs[r][q] = *(const float4*)&QKV[base + 128 + q];
  }
  if (tid < 32) dec[tid] = decay[s0 + tid];
  __syncthreads();

  {
    const int sc = (tid & 15) * 2;
    const int tr = (tid >> 4) * 2;
    float a00 = 0.f, a01 = 0.f, a10 = 0.f, a11 = 0.f;
#pragma unroll
    for (int k = 0; k < 64; k += 4) {
      const float4 q0 = *(const float4*)&Qs[tr][k];
      const float4 q1 = *(const float4*)&Qs[tr + 1][k];
      const float4 v0 = *(const float4*)&Vs[sc][k];
      const float4 v1 = *(const float4*)&Vs[sc + 1][k];
      a00 += q0.x * v0.x + q0.y * v0.y + q0.z * v0.z + q0.w * v0.w;
      a01 += q0.x * v1.x + q0.y * v1.y + q0.z * v1.z + q0.w * v1.w;
      a10 += q1.x * v0.x + q1.y * v0.y + q1.z * v0.z + q1.w * v0.w;
      a11 += q1.x * v1.x + q1.y * v1.y + q1.z * v1.z + q1.w * v1.w;
    }
    const float d0 = dec[sc], d1 = dec[sc + 1];
    Ss[tr][sc]         = (sc     <= tr)     ? a00 * d0 : 0.f;
    Ss[tr][sc + 1]     = (sc + 1 <= tr)     ? a01 * d1 : 0.f;
    Ss[tr + 1][sc]     = (sc     <= tr + 1) ? a10 * d0 : 0.f;
    Ss[tr + 1][sc + 1] = (sc + 1 <= tr + 1) ? a11 * d1 : 0.f;
  }

  float o[4][4];
#pragma unroll
  for (int i = 0; i < 4; ++i)
#pragma unroll
    for (int j = 0; j < 4; ++j) o[i][j] = 0.f;
  {
    const int kx = (tid & 15) * 4;
    const int nx = (tid >> 4) * 4;
#pragma unroll
    for (int s = 0; s < 32; ++s) {
      const float ds = dec[s];
      float4 v4 = *(const float4*)&Vs[s][kx];
      const float4 k4 = *(const float4*)&Ks[s][nx];
      v4.x *= ds; v4.y *= ds; v4.z *= ds; v4.w *= ds;
      o[0][0] += v4.x * k4.x; o[0][1] += v4.x * k4.y; o[0][2] += v4.x * k4.z; o[0][3] += v4.x * k4.w;
      o[1][0] += v4.y * k4.x; o[1][1] += v4.y * k4.y; o[1][2] += v4.y * k4.z; o[1][3] += v4.y * k4.w;
      o[2][0] += v4.z * k4.x; o[2][1] += v4.z * k4.y; o[2][2] += v4.z * k4.z; o[2][3] += v4.z * k4.w;
      o[3][0] += v4.w * k4.x; o[3][1] += v4.w * k4.y; o[3][2] += v4.w * k4.z; o[3][3] += v4.w * k4.w;
    }
  }
  __syncthreads();

  {
    const int nx = (tid & 15) * 4;
    const int tr = (tid >> 4) * 2;
    float y0[4] = {0.f, 0.f, 0.f, 0.f};
    float y1[4] = {0.f, 0.f, 0.f, 0.f};
#pragma unroll
    for (int s = 0; s < 32; s += 4) {
      const float4 sa = *(const float4*)&Ss[tr][s];
      const float4 sb = *(const float4*)&Ss[tr + 1][s];
#pragma unroll
      for (int u = 0; u < 4; ++u) {
        const float4 k4 = *(const float4*)&Ks[s + u][nx];
        const float su0 = (u == 0) ? sa.x : (u == 1) ? sa.y : (u == 2) ? sa.z : sa.w;
        const float su1 = (u == 0) ? sb.x : (u == 1) ? sb.y : (u == 2) ? sb.z : sb.w;
        y0[0] += su0 * k4.x; y0[1] += su0 * k4.y; y0[2] += su0 * k4.z; y0[3] += su0 * k4.w;
        y1[0] += su1 * k4.x; y1[1] += su1 * k4.y; y1[2] += su1 * k4.z; y1[3] += su1 * k4.w;
      }
    }
    float4 w0, w1;
    w0.x = y0[0]; w0.y = y0[1]; w0.z = y0[2]; w0.w = y0[3];
    w1.x = y1[0]; w1.y = y1[1]; w1.z = y1[2]; w1.w = y1[3];
    *(float4*)&Yb[(size_t)(b * TS + s0 + tr) * KD + nx] = w0;
    *(float4*)&Yb[(size_t)(b * TS + s0 + tr + 1) * KD + nx] = w1;
  }

  {
    const int kx = (tid & 15) * 4;
    const int nx = (tid >> 4) * 4;
    const size_t base = ((size_t)(b * 64 + c) * 64) * 64;
#pragma unroll
    for (int i = 0; i < 4; ++i) {
      float4 w;
      w.x = o[i][0]; w.y = o[i][1]; w.z = o[i][2]; w.w = o[i][3];
      *(float4*)&O[base + (size_t)(kx + i) * 64 + nx] = w;
    }
  }
}

// ---------------- C2: exclusive prefix over chunks ----------------
__global__ __launch_bounds__(256) void k_scan(const float* __restrict__ O,
                                              float* __restrict__ State) {
  const int e = blockIdx.x * 256 + threadIdx.x;
  const int b = blockIdx.y;
  const float* op = O + (size_t)b * 64 * 4096 + e;
  float* sp = State + (size_t)b * 64 * 4096 + e;
  float run = 0.f;
  for (int c = 0; c < 64; ++c) {
    sp[(size_t)c * 4096] = run;
    run += op[(size_t)c * 4096];
  }
}

// ---------------- C3: inter-chunk Y += Q @ State ----------------
__global__ __launch_bounds__(256) void k_inter(const float* __restrict__ QKV,
                                               const float* __restrict__ State,
                                               float* __restrict__ Yb) {
  const int tt = blockIdx.x;
  const int b = blockIdx.y;
  const int t0 = tt * 32;
  const int tid = threadIdx.x;
  __shared__ float Sts[64][68];
  __shared__ float Qs[32][68];
  for (int idx = tid; idx < 1024; idx += 256) {
    const int k = idx >> 4, n = (idx & 15) * 4;
    *(float4*)&Sts[k][n] =
        *(const float4*)&State[(size_t)(b * 64 + tt) * 4096 + (size_t)k * 64 + n];
  }
  for (int idx = tid; idx < 512; idx += 256) {
    const int r = idx >> 4, q = (idx & 15) * 4;
    *(float4*)&Qs[r][q] = *(const float4*)&QKV[(size_t)(b * TS + t0 + r) * 192 + q];
  }
  __syncthreads();
  const int nx = (tid & 15) * 4;
  const int tr = (tid >> 4) * 2;
  float y0[4] = {0.f, 0.f, 0.f, 0.f};
  float y1[4] = {0.f, 0.f, 0.f, 0.f};
#pragma unroll
  for (int k = 0; k < 64; k += 4) {
    const float4 q0 = *(const float4*)&Qs[tr][k];
    const float4 q1 = *(const float4*)&Qs[tr + 1][k];
#pragma unroll
    for (int u = 0; u < 4; ++u) {
      const float4 st = *(const float4*)&Sts[k + u][nx];
      const float a0 = (u == 0) ? q0.x : (u == 1) ? q0.y : (u == 2) ? q0.z : q0.w;
      const float a1 = (u == 0) ? q1.x : (u == 1) ? q1.y : (u == 2) ? q1.z : q1.w;
      y0[0] += a0 * st.x; y0[1] += a0 * st.y; y0[2] += a0 * st.z; y0[3] += a0 * st.w;
      y1[0] += a1 * st.x; y1[1] += a1 * st.y; y1[2] += a1 * st.z; y1[3] += a1 * st.w;
    }
  }
  float4 p0 = *(const float4*)&Yb[(size_t)(b * TS + t0 + tr) * KD + nx];
  float4 p1 = *(const float4*)&Yb[(size_t)(b * TS + t0 + tr + 1) * KD + nx];
  p0.x += y0[0]; p0.y += y0[1]; p0.z += y0[2]; p0.w += y0[3];
  p1.x += y1[0]; p1.y += y1[1]; p1.z += y1[2]; p1.w += y1[3];
  *(float4*)&Yb[(size_t)(b * TS + t0 + tr) * KD + nx] = p0;
  *(float4*)&Yb[(size_t)(b * TS + t0 + tr + 1) * KD + nx] = p1;
}

// ---------------- D: out = Yb @ W_o + b_o ----------------
__global__ __launch_bounds__(256) void k_out(const float* __restrict__ Yb,
                                             const float* __restrict__ Wo,
                                             const float* __restrict__ bo,
                                             float* __restrict__ out) {
  const int row0 = blockIdx.x * 16;
  const int tid = threadIdx.x;
  __shared__ float Ys[16][68];
  {
    const int r = tid >> 4, q = (tid & 15) * 4;
    *(float4*)&Ys[r][q] = *(const float4*)&Yb[(size_t)(row0 + r) * KD + q];
  }
  __syncthreads();
  const int d0 = tid * 4;
  float acc[16][4];
#pragma unroll
  for (int r = 0; r < 16; ++r)
#pragma unroll
    for (int j = 0; j < 4; ++j) acc[r][j] = 0.f;
  for (int k = 0; k < 64; k += 4) {
    const float4 w0 = *(const float4*)&Wo[(size_t)(k + 0) * DM + d0];
    const float4 w1 = *(const float4*)&Wo[(size_t)(k + 1) * DM + d0];
    const float4 w2 = *(const float4*)&Wo[(size_t)(k + 2) * DM + d0];
    const float4 w3 = *(const float4*)&Wo[(size_t)(k + 3) * DM + d0];
#pragma unroll
    for (int r = 0; r < 16; ++r) {
      const float4 ys = *(const float4*)&Ys[r][k];
      acc[r][0] += ys.x * w0.x + ys.y * w1.x + ys.z * w2.x + ys.w * w3.x;
      acc[r][1] += ys.x * w0.y + ys.y * w1.y + ys.z * w2.y + ys.w * w3.y;
      acc[r][2] += ys.x * w0.z + ys.y * w1.z + ys.z * w2.z + ys.w * w3.z;
      acc[r][3] += ys.x * w0.w + ys.y * w1.w + ys.z * w2.w + ys.w * w3.w;
    }
  }
  const float4 b4 = *(const float4*)&bo[d0];
#pragma unroll
  for (int r = 0; r < 16; ++r) {
    float4 w;
    w.x = acc[r][0] + b4.x;
    w.y = acc[r][1] + b4.y;
    w.z = acc[r][2] + b4.z;
    w.w = acc[r][3] + b4.w;
    *(float4*)&out[(size_t)(row0 + r) * DM + d0] = w;
  }
}

extern "C" void kernel_launch(void* const* d_in, const int* in_sizes, int n_in,
                              void* d_out, int out_size, void* d_ws, size_t ws_size,
                              hipStream_t stream) {
  const float* x     = (const float*)d_in[0];
  const float* W_pre = (const float*)d_in[1];
  const float* b_pre = (const float*)d_in[2];
  const float* Qf    = (const float*)d_in[3];
  const float* Kf    = (const float*)d_in[4];
  const float* W_v   = (const float*)d_in[5];
  const float* b_v   = (const float*)d_in[6];
  const float* W_o   = (const float*)d_in[7];
  const float* b_o   = (const float*)d_in[8];
  const float* decay = (const float*)d_in[9];
  float* out = (float*)d_out;
  float* ws = (float*)d_ws;

  ushort* WT_hi = (ushort*)(ws + WTH_OFF);
  ushort* WT_lo = (ushort*)(ws + WTL_OFF);
  float* bcomb = ws + BC_OFF;
  float* QKV   = ws + QKV_OFF;
  float* P     = ws + P_OFF;
  float* O     = ws + O_OFF;
  float* St    = ws + ST_OFF;
  float* Yb    = ws + YB_OFF;

  k_prep_w<<<dim3(DM / 2), 512, 0, stream>>>(W_pre, Qf, Kf, W_v, b_pre, b_v,
                                             WT_hi, WT_lo, bcomb);
  k_qkv<<<dim3(NB * TS / 64, 4), 256, 0, stream>>>(x, WT_hi, WT_lo, P);
  k_red<<<dim3(NB * TS * 192 / 4 / 256), 256, 0, stream>>>(P, bcomb, QKV);
  k_chunk<<<dim3(TS / 32, NB), 256, 0, stream>>>(QKV, decay, Yb, O);
  k_scan<<<dim3(16, NB), 256, 0, stream>>>(O, St);
  k_inter<<<dim3(TS / 32, NB), 256, 0, stream>>>(QKV, St, Yb);
  k_out<<<dim3(NB * TS / 16), 256, 0, stream>>>(Yb, W_o, b_o, out);
}